// Round 11
// baseline (184.531 us; speedup 1.0000x reference)
//
#include <hip/hip_runtime.h>
#include <math.h>

#define N_FILT   80
#define FILT_DIM 251
#define KPAD     256
#define SIG_LEN  32000
#define OUT_LEN  31750
#define BATCH    32

#define STRIP    1024      // t-range per wave
#define OBS2     36        // ob row stride (dwords) for 32-col flush groups

// global x-replica layout (fp16 pairs packed in dwords)
#define XRN      16512     // dwords per (parity, batch): covers elems 0..33023
#define XRPLANE  (BATCH * XRN)
#define WS_NEED  (40960u + 2u * XRPLANE * 4u)   // fh (40 KB) + 2 parity planes

// fallback (R10) staging params
#define NREP     8
#define LROW     644

#define TWO_PI_F 6.28318530717958647692f

typedef __attribute__((ext_vector_type(8))) short    short8;   // raw 16B frag
typedef __attribute__((ext_vector_type(8))) _Float16 half8;    // fp16 A/B frag
typedef __attribute__((ext_vector_type(4))) float    float4v;  // C/D frag
typedef __attribute__((ext_vector_type(2))) float    float2v;  // store pair
typedef __attribute__((ext_vector_type(4))) unsigned uint4v;   // b128 payload

// 4-byte-aligned 16B load wrapper (global dwordx4 needs only dword align)
typedef struct __attribute__((packed, aligned(4))) { uint4v v; } uload16;

// ---------------------------------------------------------------------------
// Kernel 1: build 80 sinc band-pass filters directly in fp16.
// ---------------------------------------------------------------------------
__global__ __launch_bounds__(256) void build_filters_kernel(
    const float* __restrict__ b1, const float* __restrict__ band,
    unsigned short* __restrict__ fh)
{
    const int f = blockIdx.x;
    const int i = threadIdx.x;

    const float MINF = 50.0f / 16000.0f;
    const float fb = fabsf(b1[f]) + MINF;
    const float fe = fb + fabsf(band[f]) + MINF;

    float v = 0.0f;
    if (i < FILT_DIM) {
        int m = i - 125; m = (m < 0) ? -m : m;
        if (m == 0) v = 2.0f * fe - 2.0f * fb;
        else {
            float a1 = TWO_PI_F * fb * (float)m;
            float a2 = TWO_PI_F * fe * (float)m;
            v = 2.0f * fe * (sinf(a2) / a2) - 2.0f * fb * (sinf(a1) / a1);
        }
    }

    __shared__ float red[256];
    red[i] = (i < FILT_DIM) ? v : -INFINITY;
    __syncthreads();
    #pragma unroll
    for (int s = 128; s > 0; s >>= 1) {
        if (i < s) red[i] = fmaxf(red[i], red[i + s]);
        __syncthreads();
    }
    const float mx = red[0];

    const float w   = 0.54f - 0.46f * cosf(TWO_PI_F * (float)i / 250.0f);
    const float val = (i < FILT_DIM) ? (v / mx) * w : 0.0f;
    const _Float16 h = (_Float16)val;                 // RNE v_cvt_f16_f32
    fh[f * KPAD + i] = __builtin_bit_cast(unsigned short, h);  // pad rows = 0
}

// ---------------------------------------------------------------------------
// Kernel 1b: build 2 parity-shifted fp16 replicas of x in global memory.
// xr[p][n][d] = pack( fp16(x[n][2d+p]), fp16(x[n][2d+p+1]) ), zero-padded.
// ---------------------------------------------------------------------------
__global__ __launch_bounds__(256) void build_x_replicas_kernel(
    const float* __restrict__ x, unsigned* __restrict__ xr)
{
    const int n = blockIdx.y;
    const int d = blockIdx.x * 256 + threadIdx.x;
    if (d >= XRN) return;
    const float* xp = x + (size_t)n * SIG_LEN;
    const int e = 2 * d;
    const float v0 = (e     < SIG_LEN) ? xp[e]     : 0.0f;
    const float v1 = (e + 1 < SIG_LEN) ? xp[e + 1] : 0.0f;
    const float v2 = (e + 2 < SIG_LEN) ? xp[e + 2] : 0.0f;
    const _Float16 h0 = (_Float16)v0, h1 = (_Float16)v1, h2 = (_Float16)v2;
    union { _Float16 h[2]; unsigned u; } pe, po;
    pe.h[0] = h0; pe.h[1] = h1;
    po.h[0] = h1; po.h[1] = h2;
    xr[0 * XRPLANE + n * XRN + d] = pe.u;
    xr[1 * XRPLANE + n * XRN + d] = po.u;
}

// ---------------------------------------------------------------------------
// Kernel 2 (R11): conv as MFMA GEMM (fp16), max store concurrency.
//   C[f,t] = sum_k F[f,k] * x[t+k]
//   - NO LDS staging: B fragments load straight from the global fp16
//     parity-replicas (per-wave working set ~20 KB -> L1/L2 resident;
//     global dwordx4 needs only 4B align, so 2 replicas suffice vs 8 in LDS).
//   - block = 2 INDEPENDENT waves (wave = one (strip, fb, n) task).
//     Zero barriers anywhere.  LDS = ob only (4.6 KB).
//   - __launch_bounds__(128, 8): target <=64 VGPR -> 32 waves/CU
//     (2x R10) with stores issued continuously -> probe the
//     store-concurrency theory's ceiling.
// ---------------------------------------------------------------------------
__global__ __launch_bounds__(128, 8) void sinc_mfma_g_kernel(
    const unsigned short* __restrict__ fh,
    const unsigned* __restrict__ xr,
    float* __restrict__ out)
{
    __shared__ __align__(16) float ob[2][16 * OBS2];   // per-wave 2.3 KB

    const int tid  = threadIdx.x;
    const int wv   = tid >> 6;
    const int lane = tid & 63;

    // XCD swizzle at block granularity: 2560 blocks -> each XCD gets 320
    // consecutive tasks-pairs = 4 complete batches of output.
    const unsigned bswz = (blockIdx.x & 7u) * 320u + (blockIdx.x >> 3);
    const unsigned i    = bswz * 2u + (unsigned)wv;     // task id 0..5119
    const int n     = (int)(i / 160u);
    const int rem   = (int)(i % 160u);
    const int fb    = rem >> 5;
    const int strip = rem & 31;
    const int e0    = strip * STRIP;

    const int m = lane & 15;          // B-col (t offset) / C-col
    const int q = lane >> 4;          // quad: k = q*8+j ; C-row = q*4+reg

    // ---- A fragments: 16 filters x 256 k, fp16 (L2-resident table) ---------
    short8 Ah[8];
    {
        const unsigned short* ph = fh + (fb * 16 + m) * KPAD + q * 8;
        #pragma unroll
        for (int kb = 0; kb < 8; ++kb)
            Ah[kb] = *(const short8*)(ph + kb * 32);
    }

    // ---- B base pointer: parity replica p = m&1, dword offset --------------
    // s = e0 + 16tt + m + 8q + 32kb ; dofs = (s-p)/2 = e0/2 + 8tt + (m>>1)+4q+16kb
    const unsigned* bp = xr + (unsigned)(m & 1) * XRPLANE + (unsigned)n * XRN
                            + (unsigned)(e0 >> 1) + (unsigned)(m >> 1) + 4u * q;

    float* const obw  = &ob[wv][0];
    const int    cp   = 2 * (lane & 15);       // flush: group-local col pair
    const int    rr0  = lane >> 4;             // flush: row 0..3 (+4j)
    const size_t row0 = ((size_t)n * N_FILT + fb * 16) * OUT_LEN;

    for (int gp = 0; gp < 32; ++gp) {          // 32 groups of 32 cols
        #pragma unroll
        for (int tl = 0; tl < 2; ++tl) {
            const int tt = gp * 2 + tl;
            float4v a0 = {0.f,0.f,0.f,0.f}, a1 = {0.f,0.f,0.f,0.f};
            const unsigned o0 = 8u * (unsigned)tt;
            #pragma unroll
            for (int kk = 0; kk < 4; ++kk) {   // kb = 2kk (a0), 2kk+1 (a1)
                const uint4v b0 = ((const uload16*)(bp + o0 + 32u*kk))->v;
                const uint4v b1 = ((const uload16*)(bp + o0 + 32u*kk + 16u))->v;
                a0 = __builtin_amdgcn_mfma_f32_16x16x32_f16(
                         __builtin_bit_cast(half8, Ah[2*kk]),
                         __builtin_bit_cast(half8, b0), a0, 0, 0, 0);
                a1 = __builtin_amdgcn_mfma_f32_16x16x32_f16(
                         __builtin_bit_cast(half8, Ah[2*kk+1]),
                         __builtin_bit_cast(half8, b1), a1, 0, 0, 0);
            }
            const int oc = tl * 16 + m;        // group-local col
            #pragma unroll
            for (int rg = 0; rg < 4; ++rg)
                obw[(q * 4 + rg) * OBS2 + oc] = a0[rg] + a1[rg];
        }

        // flush group: 4 float2 stores (4 rows x 128 B each)
        const int t0 = e0 + gp * 32 + cp;      // even; OUT_LEN even
        if (t0 + 1 < OUT_LEN) {
            #pragma unroll
            for (int j = 0; j < 4; ++j) {
                const int row = j * 4 + rr0;
                const float2v v = *(const float2v*)(&obw[row * OBS2 + cp]);
                *(float2v*)(out + row0 + (size_t)row * OUT_LEN + t0) = v;
            }
        }
    }
}

// ---------------------------------------------------------------------------
// Fallback conv kernel (R10, proven 85.4 us) -- used if ws too small.
// ---------------------------------------------------------------------------
__global__ __launch_bounds__(320, 5) void sinc_mfma_kernel(
    const float* __restrict__ x,
    const unsigned short* __restrict__ fh,
    float* __restrict__ out)
{
    __shared__ __align__(16) unsigned xf[NREP * LROW];
    __shared__ __align__(16) float    ob[5][16 * OBS2];

    const int tid = threadIdx.x;
    const unsigned raw = blockIdx.x;
    const unsigned swz = (raw & 7u) * 128u + (raw >> 3);
    const int strip = (int)(swz & 31u);
    const int n     = (int)(swz >> 5);
    const int e0    = strip * STRIP;
    const float* xp = x + (size_t)n * SIG_LEN;

    for (int d = tid; d < LROW; d += 320) {
        const int g = e0 + 2 * d;
        float v0, v1, v2;
        if (g + 2 < SIG_LEN) {
            float2 p = *(const float2*)(xp + g);
            v0 = p.x; v1 = p.y; v2 = xp[g + 2];
        } else {
            v0 = (g     < SIG_LEN) ? xp[g]     : 0.0f;
            v1 = (g + 1 < SIG_LEN) ? xp[g + 1] : 0.0f;
            v2 = (g + 2 < SIG_LEN) ? xp[g + 2] : 0.0f;
        }
        const _Float16 h0 = (_Float16)v0, h1 = (_Float16)v1, h2 = (_Float16)v2;
        union { _Float16 h[2]; unsigned u; } pe, po;
        pe.h[0] = h0; pe.h[1] = h1;
        po.h[0] = h1; po.h[1] = h2;
        xf[0 * LROW + d] = pe.u;
        xf[1 * LROW + d] = po.u;
        if (d >= 1) { xf[2 * LROW + d - 1] = pe.u;
                      xf[3 * LROW + d - 1] = po.u; }
        if (d >= 2) { xf[4 * LROW + d - 2] = pe.u;
                      xf[5 * LROW + d - 2] = po.u; }
        if (d >= 3) { xf[6 * LROW + d - 3] = pe.u;
                      xf[7 * LROW + d - 3] = po.u; }
    }

    const int lane = tid & 63;
    const int w    = tid >> 6;
    const int m    = lane & 15;
    const int q    = lane >> 4;
    short8 Ah[8];
    {
        const unsigned short* ph = fh + (w * 16 + m) * KPAD + q * 8;
        #pragma unroll
        for (int kb = 0; kb < 8; ++kb)
            Ah[kb] = *(const short8*)(ph + kb * 32);
    }
    __syncthreads();

    const int r = m & 7;
    const unsigned base = (unsigned)(r * LROW + 4 * (m >> 3) + 4 * q);

    float* const obw  = &ob[w][0];
    const int    cp   = 2 * (lane & 15);
    const int    rr0  = lane >> 4;
    const size_t row0 = ((size_t)n * N_FILT + w * 16) * OUT_LEN;

    for (int gp = 0; gp < 32; ++gp) {
        #pragma unroll
        for (int tl = 0; tl < 2; ++tl) {
            const int tt = gp * 2 + tl;
            float4v a0 = {0.f,0.f,0.f,0.f}, a1 = {0.f,0.f,0.f,0.f};
            const unsigned o0 = base + 8u * (unsigned)tt;
            #pragma unroll
            for (int kk = 0; kk < 4; ++kk) {
                a0 = __builtin_amdgcn_mfma_f32_16x16x32_f16(
                         __builtin_bit_cast(half8, Ah[2*kk]),
                         __builtin_bit_cast(half8, *(const uint4*)(&xf[o0 + 32*kk])),
                         a0, 0, 0, 0);
                a1 = __builtin_amdgcn_mfma_f32_16x16x32_f16(
                         __builtin_bit_cast(half8, Ah[2*kk+1]),
                         __builtin_bit_cast(half8, *(const uint4*)(&xf[o0 + 32*kk + 16])),
                         a1, 0, 0, 0);
            }
            const int oc = tl * 16 + m;
            #pragma unroll
            for (int rg = 0; rg < 4; ++rg)
                obw[(q * 4 + rg) * OBS2 + oc] = a0[rg] + a1[rg];
        }

        const int t0 = e0 + gp * 32 + cp;
        if (t0 + 1 < OUT_LEN) {
            #pragma unroll
            for (int j = 0; j < 4; ++j) {
                const int row = j * 4 + rr0;
                const float2v v = *(const float2v*)(&obw[row * OBS2 + cp]);
                *(float2v*)(out + row0 + (size_t)row * OUT_LEN + t0) = v;
            }
        }
    }
}

// ---------------------------------------------------------------------------
extern "C" void kernel_launch(void* const* d_in, const int* in_sizes, int n_in,
                              void* d_out, int out_size, void* d_ws, size_t ws_size,
                              hipStream_t stream)
{
    const float* x    = (const float*)d_in[0];
    const float* b1   = (const float*)d_in[1];
    const float* band = (const float*)d_in[2];
    float* outp = (float*)d_out;

    unsigned short* fh = (unsigned short*)d_ws;              // 40 KB
    unsigned*       xr = (unsigned*)((char*)d_ws + 40960);   // 4.2 MB replicas

    build_filters_kernel<<<dim3(N_FILT), dim3(256), 0, stream>>>(b1, band, fh);

    if (ws_size >= (size_t)WS_NEED) {
        build_x_replicas_kernel<<<dim3((XRN + 255) / 256, BATCH), dim3(256),
                                  0, stream>>>(x, xr);
        sinc_mfma_g_kernel<<<dim3(2560), dim3(128), 0, stream>>>(fh, xr, outp);
    } else {
        sinc_mfma_kernel<<<dim3(1024), dim3(320), 0, stream>>>(x, fh, outp);
    }
}

// Round 12
// 103.078 us; speedup vs baseline: 1.7902x; 1.7902x over previous
//
#include <hip/hip_runtime.h>
#include <math.h>

#define N_FILT   80
#define FILT_DIM 251
#define KPAD     256
#define SIG_LEN  32000
#define OUT_LEN  31750
#define BATCH    32
#define TPB      320       // 5 waves: wave w owns filter-block fb = w

#define STRIP    1024      // t-range per wave
#define LROW4    644       // dwords per replica (4 replicas, b64-aligned reads)
#define OBS2     36        // ob row stride (dwords) for 32-col flush groups

#define TWO_PI_F 6.28318530717958647692f

typedef __attribute__((ext_vector_type(8))) short    short8;   // raw 16B frag
typedef __attribute__((ext_vector_type(8))) _Float16 half8;    // fp16 A/B frag
typedef __attribute__((ext_vector_type(4))) float    float4v;  // C/D frag
typedef __attribute__((ext_vector_type(2))) float    float2v;  // store pair
typedef __attribute__((ext_vector_type(2))) unsigned uint2v;   // b64 payload
typedef __attribute__((ext_vector_type(4))) unsigned uint4v;   // frag dwords

// ---------------------------------------------------------------------------
// Kernel 1: build 80 sinc band-pass filters directly in fp16.
// ---------------------------------------------------------------------------
__global__ __launch_bounds__(256) void build_filters_kernel(
    const float* __restrict__ b1, const float* __restrict__ band,
    unsigned short* __restrict__ fh)
{
    const int f = blockIdx.x;
    const int i = threadIdx.x;

    const float MINF = 50.0f / 16000.0f;
    const float fb = fabsf(b1[f]) + MINF;
    const float fe = fb + fabsf(band[f]) + MINF;

    float v = 0.0f;
    if (i < FILT_DIM) {
        int m = i - 125; m = (m < 0) ? -m : m;
        if (m == 0) v = 2.0f * fe - 2.0f * fb;
        else {
            float a1 = TWO_PI_F * fb * (float)m;
            float a2 = TWO_PI_F * fe * (float)m;
            v = 2.0f * fe * (sinf(a2) / a2) - 2.0f * fb * (sinf(a1) / a1);
        }
    }

    __shared__ float red[256];
    red[i] = (i < FILT_DIM) ? v : -INFINITY;
    __syncthreads();
    #pragma unroll
    for (int s = 128; s > 0; s >>= 1) {
        if (i < s) red[i] = fmaxf(red[i], red[i + s]);
        __syncthreads();
    }
    const float mx = red[0];

    const float w   = 0.54f - 0.46f * cosf(TWO_PI_F * (float)i / 250.0f);
    const float val = (i < FILT_DIM) ? (v / mx) * w : 0.0f;
    const _Float16 h = (_Float16)val;                 // RNE v_cvt_f16_f32
    fh[f * KPAD + i] = __builtin_bit_cast(unsigned short, h);  // pad rows = 0
}

// ---------------------------------------------------------------------------
// Kernel 2 (R12): conv as MFMA GEMM (fp16), occupancy-maximized, clean probe
// of the store-concurrency theory (R11's global-B attempt broke the load
// path; this keeps R10's proven LDS-staged B).
//   - staging: 4 parity replicas + 2x ds_read_b64 per fragment (b64 needs
//     only 8B align) -> staging LDS 20.6 -> 10.3 KB, total 21.8 KB ->
//     LDS fits 7 blocks/CU.
//   - __launch_bounds__(320, 8): VGPR <= 64 -> 8 waves/SIMD -> wave cap 32:
//     6 blocks = 30 waves/CU (R10: 20).
//   Rest identical to R10: 5 waves, wave w owns fb=w; ONE barrier;
//   wave-private ob gather + 4x float2 flush per 2-tile group.
// ---------------------------------------------------------------------------
__global__ __launch_bounds__(TPB, 8) void sinc_mfma_kernel(
    const float* __restrict__ x,
    const unsigned short* __restrict__ fh,
    float* __restrict__ out)
{
    __shared__ __align__(16) unsigned xf[4 * LROW4];       // 10.3 KB
    __shared__ __align__(16) float    ob[5][16 * OBS2];    // 11.5 KB

    const int tid = threadIdx.x;
    // XCD swizzle: raw%8 = XCD -> each XCD owns 128 contiguous (strip,n)
    // blocks = 4 complete batches.
    const unsigned raw = blockIdx.x;
    const unsigned swz = (raw & 7u) * 128u + (raw >> 3);
    const int strip = (int)(swz & 31u);
    const int n     = (int)(swz >> 5);
    const int e0    = strip * STRIP;
    const float* xp = x + (size_t)n * SIG_LEN;

    // ---- stage x: fp16, 4 parity replicas: xf[r][d] = elems (2d+r, 2d+r+1)
    for (int d = tid; d < LROW4; d += TPB) {
        const int g = e0 + 2 * d;
        float v0, v1, v2, v3, v4;
        if (g + 4 < SIG_LEN) {
            float2 p01 = *(const float2*)(xp + g);
            float2 p23 = *(const float2*)(xp + g + 2);
            v0 = p01.x; v1 = p01.y; v2 = p23.x; v3 = p23.y; v4 = xp[g + 4];
        } else {
            v0 = (g     < SIG_LEN) ? xp[g]     : 0.0f;
            v1 = (g + 1 < SIG_LEN) ? xp[g + 1] : 0.0f;
            v2 = (g + 2 < SIG_LEN) ? xp[g + 2] : 0.0f;
            v3 = (g + 3 < SIG_LEN) ? xp[g + 3] : 0.0f;
            v4 = (g + 4 < SIG_LEN) ? xp[g + 4] : 0.0f;
        }
        const _Float16 h0 = (_Float16)v0, h1 = (_Float16)v1, h2 = (_Float16)v2;
        const _Float16 h3 = (_Float16)v3, h4 = (_Float16)v4;
        union { _Float16 h[2]; unsigned u; } p0, p1, p2, p3;
        p0.h[0] = h0; p0.h[1] = h1;
        p1.h[0] = h1; p1.h[1] = h2;
        p2.h[0] = h2; p2.h[1] = h3;
        p3.h[0] = h3; p3.h[1] = h4;
        xf[0 * LROW4 + d] = p0.u;
        xf[1 * LROW4 + d] = p1.u;
        xf[2 * LROW4 + d] = p2.u;
        xf[3 * LROW4 + d] = p3.u;
    }

    // ---- A fragments: wave w reads its 16 filters (fb = w) ------------------
    const int lane = tid & 63;
    const int w    = tid >> 6;        // wave id == filter-block
    const int m    = lane & 15;       // B-col (t offset) / C-col
    const int q    = lane >> 4;       // quad: k = q*8+j ; C-row = q*4+reg
    short8 Ah[8];
    {
        const unsigned short* ph = fh + (w * 16 + m) * KPAD + q * 8;
        #pragma unroll
        for (int kb = 0; kb < 8; ++kb)
            Ah[kb] = *(const short8*)(ph + kb * 32);
    }
    __syncthreads();                  // the ONLY barrier

    // ---- main loop: 64 t-tiles in 32 groups of 2, flush per group ----------
    // element start s = 16tt + m + 8q + 32kb ; replica r = m&3
    // frag = b64 @ d0, b64 @ d0+2,  d0 = r*LROW4 + 2*(m>>2) + 4q + 8tt + 16kb
    const int r = m & 3;
    const unsigned base = (unsigned)(r * LROW4 + 2 * (m >> 2) + 4 * q);

    float* const obw  = &ob[w][0];
    const int    cp   = 2 * (lane & 15);       // flush: group-local col pair
    const int    rr0  = lane >> 4;             // flush: row 0..3 (+4j)
    const size_t row0 = ((size_t)n * N_FILT + w * 16) * OUT_LEN;

    for (int gp = 0; gp < 32; ++gp) {          // 32 groups of 32 cols
        #pragma unroll
        for (int tl = 0; tl < 2; ++tl) {
            const int tt = gp * 2 + tl;
            float4v a0 = {0.f,0.f,0.f,0.f}, a1 = {0.f,0.f,0.f,0.f};
            const unsigned o0 = base + 8u * (unsigned)tt;
            #pragma unroll
            for (int kk = 0; kk < 4; ++kk) {   // kb = 2kk (a0), 2kk+1 (a1)
                const unsigned oa = o0 + 32u * kk;        // kb = 2kk
                const unsigned ob_ = oa + 16u;            // kb = 2kk+1
                const uint2v a_lo = *(const uint2v*)(&xf[oa]);
                const uint2v a_hi = *(const uint2v*)(&xf[oa + 2]);
                const uint2v b_lo = *(const uint2v*)(&xf[ob_]);
                const uint2v b_hi = *(const uint2v*)(&xf[ob_ + 2]);
                const uint4v fa = {a_lo.x, a_lo.y, a_hi.x, a_hi.y};
                const uint4v fb = {b_lo.x, b_lo.y, b_hi.x, b_hi.y};
                a0 = __builtin_amdgcn_mfma_f32_16x16x32_f16(
                         __builtin_bit_cast(half8, Ah[2*kk]),
                         __builtin_bit_cast(half8, fa), a0, 0, 0, 0);
                a1 = __builtin_amdgcn_mfma_f32_16x16x32_f16(
                         __builtin_bit_cast(half8, Ah[2*kk+1]),
                         __builtin_bit_cast(half8, fb), a1, 0, 0, 0);
            }
            const int oc = tl * 16 + m;        // group-local col
            #pragma unroll
            for (int rg = 0; rg < 4; ++rg)
                obw[(q * 4 + rg) * OBS2 + oc] = a0[rg] + a1[rg];
        }

        // flush group: 4 float2 stores (4 rows x 128 B each)
        const int t0 = e0 + gp * 32 + cp;      // even; OUT_LEN even
        if (t0 + 1 < OUT_LEN) {
            #pragma unroll
            for (int j = 0; j < 4; ++j) {
                const int row = j * 4 + rr0;
                const float2v v = *(const float2v*)(&obw[row * OBS2 + cp]);
                *(float2v*)(out + row0 + (size_t)row * OUT_LEN + t0) = v;
            }
        }
    }
}

// ---------------------------------------------------------------------------
extern "C" void kernel_launch(void* const* d_in, const int* in_sizes, int n_in,
                              void* d_out, int out_size, void* d_ws, size_t ws_size,
                              hipStream_t stream)
{
    const float* x    = (const float*)d_in[0];
    const float* b1   = (const float*)d_in[1];
    const float* band = (const float*)d_in[2];
    float* outp = (float*)d_out;

    unsigned short* fh = (unsigned short*)d_ws;          // 80*256*2 B = 40 KB

    build_filters_kernel<<<dim3(N_FILT), dim3(256), 0, stream>>>(b1, band, fh);

    dim3 grid(1024);                                     // (strip, n) swizzled
    sinc_mfma_kernel<<<grid, dim3(TPB), 0, stream>>>(x, fh, outp);
}

// Round 14
// 84.970 us; speedup vs baseline: 2.1717x; 1.2131x over previous
//
#include <hip/hip_runtime.h>
#include <math.h>

#define N_FILT   80
#define FILT_DIM 251
#define KPAD     256
#define SIG_LEN  32000
#define OUT_LEN  31750
#define BATCH    32
#define TPB      320       // 5 waves: wave w owns filter-block fb = w

#define STRIP    1024      // t-range per block
#define NREP     8         // shifted replicas -> every window is 16B aligned
#define LROW     644       // dwords per replica: %4==0 (16B align), /4 odd (bank spread)
#define OBS2     36        // ob row stride (dwords) for 32-col flush groups

#define TWO_PI_F 6.28318530717958647692f

typedef __attribute__((ext_vector_type(8))) short    short8;   // raw 16B frag
typedef __attribute__((ext_vector_type(8))) _Float16 half8;    // fp16 A/B frag
typedef __attribute__((ext_vector_type(4))) float    float4v;  // C/D frag
typedef __attribute__((ext_vector_type(2))) float    float2v;  // store pair

// ---------------------------------------------------------------------------
// Kernel 1: build 80 sinc band-pass filters directly in fp16.
// ---------------------------------------------------------------------------
__global__ __launch_bounds__(256) void build_filters_kernel(
    const float* __restrict__ b1, const float* __restrict__ band,
    unsigned short* __restrict__ fh)
{
    const int f = blockIdx.x;
    const int i = threadIdx.x;

    const float MINF = 50.0f / 16000.0f;
    const float fb = fabsf(b1[f]) + MINF;
    const float fe = fb + fabsf(band[f]) + MINF;

    float v = 0.0f;
    if (i < FILT_DIM) {
        int m = i - 125; m = (m < 0) ? -m : m;
        if (m == 0) v = 2.0f * fe - 2.0f * fb;
        else {
            float a1 = TWO_PI_F * fb * (float)m;
            float a2 = TWO_PI_F * fe * (float)m;
            v = 2.0f * fe * (sinf(a2) / a2) - 2.0f * fb * (sinf(a1) / a1);
        }
    }

    __shared__ float red[256];
    red[i] = (i < FILT_DIM) ? v : -INFINITY;
    __syncthreads();
    #pragma unroll
    for (int s = 128; s > 0; s >>= 1) {
        if (i < s) red[i] = fmaxf(red[i], red[i + s]);
        __syncthreads();
    }
    const float mx = red[0];

    const float w   = 0.54f - 0.46f * cosf(TWO_PI_F * (float)i / 250.0f);
    const float val = (i < FILT_DIM) ? (v / mx) * w : 0.0f;
    const _Float16 h = (_Float16)val;                 // RNE v_cvt_f16_f32
    fh[f * KPAD + i] = __builtin_bit_cast(unsigned short, h);  // pad rows = 0
}

// ---------------------------------------------------------------------------
// Kernel 2 (R13): conv as MFMA GEMM (fp16) -- R10 body EXACTLY, with
// __launch_bounds__(320,7): VGPR <= 73 so one SIMD can host 7 waves,
// letting a 5th block (25 waves/CU, was 20) fit under the 32,768 B LDS
// line (xf 20,608 + ob 11,520 = 32,128 B).  Single-variable probe of the
// store-concurrency ladder: 15w->93.2us, 20w->85.4us, 25w->?
//   5 waves, wave w owns fb=w; staging once; ONE barrier; wave-private ob
//   gather + 4x float2 flush per 2-tile group; no vmcnt drains.
// ---------------------------------------------------------------------------
__global__ __launch_bounds__(TPB, 7) void sinc_mfma_kernel(
    const float* __restrict__ x,
    const unsigned short* __restrict__ fh,
    float* __restrict__ out)
{
    __shared__ __align__(16) unsigned xf[NREP * LROW];     // 20.6 KB
    __shared__ __align__(16) float    ob[5][16 * OBS2];    // 11.5 KB

    const int tid = threadIdx.x;
    // XCD swizzle: raw%8 = XCD -> each XCD owns 128 contiguous (strip,n)
    // blocks = 4 complete batches.
    const unsigned raw = blockIdx.x;
    const unsigned swz = (raw & 7u) * 128u + (raw >> 3);
    const int strip = (int)(swz & 31u);
    const int n     = (int)(swz >> 5);
    const int e0    = strip * STRIP;
    const float* xp = x + (size_t)n * SIG_LEN;

    // ---- stage x: fp16, 8 shifted replicas (replica r, dword d = elems 2d+r,2d+r+1)
    for (int d = tid; d < LROW; d += TPB) {
        const int g = e0 + 2 * d;
        float v0, v1, v2;
        if (g + 2 < SIG_LEN) {
            float2 p = *(const float2*)(xp + g);
            v0 = p.x; v1 = p.y; v2 = xp[g + 2];
        } else {
            v0 = (g     < SIG_LEN) ? xp[g]     : 0.0f;
            v1 = (g + 1 < SIG_LEN) ? xp[g + 1] : 0.0f;
            v2 = (g + 2 < SIG_LEN) ? xp[g + 2] : 0.0f;
        }
        const _Float16 h0 = (_Float16)v0, h1 = (_Float16)v1, h2 = (_Float16)v2;
        union { _Float16 h[2]; unsigned u; } pe, po;
        pe.h[0] = h0; pe.h[1] = h1;          // elems 2d, 2d+1
        po.h[0] = h1; po.h[1] = h2;          // elems 2d+1, 2d+2
        xf[0 * LROW + d] = pe.u;                                  // r=0
        xf[1 * LROW + d] = po.u;                                  // r=1
        if (d >= 1) { xf[2 * LROW + d - 1] = pe.u;                // r=2
                      xf[3 * LROW + d - 1] = po.u; }              // r=3
        if (d >= 2) { xf[4 * LROW + d - 2] = pe.u;                // r=4
                      xf[5 * LROW + d - 2] = po.u; }              // r=5
        if (d >= 3) { xf[6 * LROW + d - 3] = pe.u;                // r=6
                      xf[7 * LROW + d - 3] = po.u; }              // r=7
    }

    // ---- A fragments: wave w reads its 16 filters (fb = w) ------------------
    const int lane = tid & 63;
    const int w    = tid >> 6;        // wave id == filter-block
    const int m    = lane & 15;       // B-col (t offset) / C-col
    const int q    = lane >> 4;       // quad: k = q*8+j ; C-row = q*4+reg
    short8 Ah[8];
    {
        const unsigned short* ph = fh + (w * 16 + m) * KPAD + q * 8;
        #pragma unroll
        for (int kb = 0; kb < 8; ++kb)
            Ah[kb] = *(const short8*)(ph + kb * 32);
    }
    __syncthreads();                  // the ONLY barrier

    // ---- main loop: 64 t-tiles in 32 groups of 2, flush per group ----------
    // element start s = 16tt + m + 8q + 32kb ; replica r = m&7
    // frag dword offset = base + 8*tt + 16*kb  (16B-aligned, balanced
    // 8 lanes per 16B bank group per b128 -> conflict-free)
    const int r = m & 7;
    const unsigned base = (unsigned)(r * LROW + 4 * (m >> 3) + 4 * q);

    float* const obw  = &ob[w][0];
    const int    cp   = 2 * (lane & 15);       // flush: group-local col pair
    const int    rr0  = lane >> 4;             // flush: row 0..3 (+4j)
    const size_t row0 = ((size_t)n * N_FILT + w * 16) * OUT_LEN;

    for (int gp = 0; gp < 32; ++gp) {          // 32 groups of 32 cols
        #pragma unroll
        for (int tl = 0; tl < 2; ++tl) {
            const int tt = gp * 2 + tl;
            float4v a0 = {0.f,0.f,0.f,0.f}, a1 = {0.f,0.f,0.f,0.f};
            const unsigned o0 = base + 8u * (unsigned)tt;
            #pragma unroll
            for (int kk = 0; kk < 4; ++kk) {   // kb = 2kk (a0), 2kk+1 (a1)
                a0 = __builtin_amdgcn_mfma_f32_16x16x32_f16(
                         __builtin_bit_cast(half8, Ah[2*kk]),
                         __builtin_bit_cast(half8, *(const uint4*)(&xf[o0 + 32*kk])),
                         a0, 0, 0, 0);
                a1 = __builtin_amdgcn_mfma_f32_16x16x32_f16(
                         __builtin_bit_cast(half8, Ah[2*kk+1]),
                         __builtin_bit_cast(half8, *(const uint4*)(&xf[o0 + 32*kk + 16])),
                         a1, 0, 0, 0);
            }
            const int oc = tl * 16 + m;        // group-local col
            #pragma unroll
            for (int rg = 0; rg < 4; ++rg)
                obw[(q * 4 + rg) * OBS2 + oc] = a0[rg] + a1[rg];
        }

        // flush group: 4 float2 stores (4 rows x 128 B each), conflict-free
        const int t0 = e0 + gp * 32 + cp;      // even; OUT_LEN even
        if (t0 + 1 < OUT_LEN) {
            #pragma unroll
            for (int j = 0; j < 4; ++j) {
                const int row = j * 4 + rr0;
                const float2v v = *(const float2v*)(&obw[row * OBS2 + cp]);
                *(float2v*)(out + row0 + (size_t)row * OUT_LEN + t0) = v;
            }
        }
    }
}

// ---------------------------------------------------------------------------
extern "C" void kernel_launch(void* const* d_in, const int* in_sizes, int n_in,
                              void* d_out, int out_size, void* d_ws, size_t ws_size,
                              hipStream_t stream)
{
    const float* x    = (const float*)d_in[0];
    const float* b1   = (const float*)d_in[1];
    const float* band = (const float*)d_in[2];
    float* outp = (float*)d_out;

    unsigned short* fh = (unsigned short*)d_ws;          // 80*256*2 B = 40 KB

    build_filters_kernel<<<dim3(N_FILT), dim3(256), 0, stream>>>(b1, band, fh);

    dim3 grid(1024);                                     // (strip, n) swizzled
    sinc_mfma_kernel<<<grid, dim3(TPB), 0, stream>>>(x, fh, outp);
}